// Round 15
// baseline (392.842 us; speedup 1.0000x reference)
//
#include <hip/hip_runtime.h>
#include <hip/hip_bf16.h>
#include <hip/hip_fp8.h>

// SlidingFFAgent: fused 5-layer MLP + sliding window, MFMA pipeline.
// Round 15: h1q8 read/write XOR swizzle (kills enc stage-2 4-way bank
// conflicts); dec h4s swizzle widened to 4-bit; enc_hi fused into enc as
// blocks 0..223 (one launch fewer, tail overlapped).

#define DEVI __device__ __forceinline__

typedef float f32x4 __attribute__((ext_vector_type(4)));
typedef short s16x8 __attribute__((ext_vector_type(8)));
typedef short s16x4 __attribute__((ext_vector_type(4)));
typedef long long i64;
typedef unsigned long long u64;

#define ROWS 131072
#define SEQ_T 263

// packed bf16 weight offsets (in shorts)
#define W2P_OFF 524288
#define W5P_OFF 1441792

#define W3P8_BYTE_OFF 2916352           // fp8 w3 frags (512KB)
#define SEQ8_BYTE_OFF 3440640           // fp8 seq: 512 ba x 263 x 128B
#define W4P8_BYTE_OFF 20971520          // fp8 w4 frags (256KB)
#define BIG_BYTE_OFF 37388288           // h3p8; head doubles as fp8 w1/w2 for enc

DEVI short f2bf(float f) {
  union { __hip_bfloat16 h; short s; } u;
  u.h = __float2bfloat16(f);
  return u.s;
}
DEVI float bf2f(short s) {
  union { float f; unsigned int u; } v;
  v.u = ((unsigned int)(unsigned short)s) << 16;
  return v.f;
}

DEVI unsigned int f2e4(float f) {
  union { __hip_fp8_e4m3 h; unsigned char c; } u;
  u.h = __hip_fp8_e4m3(f);
  return (unsigned int)u.c;
}

#if __has_builtin(__builtin_amdgcn_cvt_pk_fp8_f32)
DEVI unsigned int pk4e4(float a, float b, float c, float d) {
  int v = 0;
  v = __builtin_amdgcn_cvt_pk_fp8_f32(a, b, v, false);
  v = __builtin_amdgcn_cvt_pk_fp8_f32(c, d, v, true);
  return (unsigned int)v;
}
#else
DEVI unsigned int pk4e4(float a, float b, float c, float d) {
  return f2e4(a) | (f2e4(b) << 8) | (f2e4(c) << 16) | (f2e4(d) << 24);
}
#endif

DEVI f32x4 MFMA(s16x8 a, s16x8 b, f32x4 c) {
  return __builtin_amdgcn_mfma_f32_16x16x32_bf16(a, b, c, 0, 0, 0);
}
DEVI f32x4 MFMA8(i64 a, i64 b, f32x4 c) {
  return __builtin_amdgcn_mfma_f32_16x16x32_fp8_fp8(a, b, c, 0, 0, 0);
}

// ---------------- merged prep: bf16 packs (w1/w2/w5) + fp8 packs (w1..w4) + hid ----------------
__global__ __launch_bounds__(256) void prep_kernel(
    const float* __restrict__ w1, const float* __restrict__ w2,
    const float* __restrict__ w3, const float* __restrict__ w4,
    const float* __restrict__ w5, const float* __restrict__ hid,
    short* __restrict__ wp, unsigned char* __restrict__ wp8,
    unsigned char* __restrict__ w3p8, unsigned char* __restrict__ w4p8,
    unsigned char* __restrict__ seq8)
{
  int t0 = blockIdx.x * 256 + threadIdx.x;
  if (t0 < 671744) {
    int idx = t0;
    const float* src; int sh, Nsrc, local; long dsto;
    if (idx < W2P_OFF)     { src = w1; sh = 4; Nsrc = 1024; local = idx;           dsto = idx; }
    else if (idx < 655360) { src = w2; sh = 5; Nsrc = 128;  local = idx - W2P_OFF; dsto = idx; }
    else                   { src = w5; sh = 4; Nsrc = 30;   local = idx - 655360;  dsto = W5P_OFF + (idx - 655360); }
    int j    = local & 7;
    int lane = (local >> 3) & 63;
    int rest = local >> 9;
    int k0   = rest & ((1 << sh) - 1);
    int n0   = rest >> sh;
    int k = (k0 << 5) + ((lane >> 4) << 3) + j;
    int n = (n0 << 4) + (lane & 15);
    float v = (n < Nsrc) ? src[k * Nsrc + n] : 0.f;
    wp[dsto] = f2bf(v);
  } else if (t0 < 851968) {
    int t = t0 - 671744;
    const float* src; int nkshift, Nsrc, dt; unsigned char* dst;
    if (t < 65536)       { src = w1; dt = t;          nkshift = 4; Nsrc = 1024; dst = wp8; }
    else if (t < 81920)  { src = w2; dt = t - 65536;  nkshift = 5; Nsrc = 128;  dst = wp8 + 524288; }
    else if (t < 147456) { src = w3; dt = t - 81920;  nkshift = 5; Nsrc = 512;  dst = w3p8; }
    else                 { src = w4; dt = t - 147456; nkshift = 4; Nsrc = 512;  dst = w4p8; }
    int lane = dt & 63;
    int rest = dt >> 6;
    int k0   = rest & ((1 << nkshift) - 1);
    int n0   = rest >> nkshift;
    int kb = (k0 << 5) + ((lane >> 4) << 3);
    int n  = (n0 << 4) + (lane & 15);
    float v[8];
    #pragma unroll
    for (int j = 0; j < 8; ++j) v[j] = src[(kb + j) * Nsrc + n];
    u64 pk = (u64)pk4e4(v[0], v[1], v[2], v[3])
           | ((u64)pk4e4(v[4], v[5], v[6], v[7]) << 32);
    *(u64*)(dst + (long)dt * 8) = pk;
  } else {
    int t = t0 - 851968;   // 57344 total
    int j = t & 15;
    int r = t >> 4;
    int i = r % 7;
    int ba = r / 7;
    int s = j ^ i;
    const float* src = hid + (r << 7) + (j << 3);
    f32x4 a = *(const f32x4*)src;
    f32x4 b = *(const f32x4*)(src + 4);
    u64 pk = (u64)pk4e4(a[0], a[1], a[2], a[3])
           | ((u64)pk4e4(b[0], b[1], b[2], b[3]) << 32);
    *(u64*)(seq8 + (ba * SEQ_T + i) * 128 + s * 8) = pk;
  }
}

// ---------------- fused encoder: blocks 0..223 = bf16 enc_hi (output 1);
//                   blocks 224.. = fp8 enc main (seq). 64KB smem union. ----
__global__ __launch_bounds__(512, 4) void enc_kernel(
    const float* __restrict__ inp, const unsigned char* __restrict__ w1p8,
    const float* __restrict__ b1, const unsigned char* __restrict__ w2p8,
    const float* __restrict__ b2, unsigned char* __restrict__ seq8,
    const short* __restrict__ w1p, const short* __restrict__ w2p,
    float* __restrict__ out)
{
  __shared__ char smem[65536] __attribute__((aligned(16)));
  const int tid = threadIdx.x;
  const int lane = tid & 63, wv = tid >> 6;     // wave 0..7
  const int l15 = lane & 15, lg = lane >> 4;
  f32x4 z = {0.f, 0.f, 0.f, 0.f};

  if (blockIdx.x < 224) {
    // ===== bf16 enc_hi: window frames t=249..255 -> output 1 =====
    short* As  = (short*)smem;            // [k2 64][m 16][8] 16KB
    short* h1s = (short*)(smem + 16384);  // [k2 128][m 16][8] 32KB
    const int b = blockIdx.x / 7, ti = blockIdx.x % 7;
    const int t = 249 + ti;
    const long row0 = (long)b * 4096 + t * 16;

    #pragma unroll
    for (int it = 0; it < 2; ++it) {
      int c = it * 512 + tid;            // 1024 chunks (16 rows x 64)
      int m = c >> 6, j = c & 63;
      const float* s = inp + (row0 + m) * 512 + j * 8;
      f32x4 v0 = *(const f32x4*)s;
      f32x4 v1 = *(const f32x4*)(s + 4);
      s16x8 o;
      o[0]=f2bf(v0[0]); o[1]=f2bf(v0[1]); o[2]=f2bf(v0[2]); o[3]=f2bf(v0[3]);
      o[4]=f2bf(v1[0]); o[5]=f2bf(v1[1]); o[6]=f2bf(v1[2]); o[7]=f2bf(v1[3]);
      *(s16x8*)((char*)As + (j << 8) + (((m ^ (j & 15)) & 15) << 4)) = o;
    }
    __syncthreads();

    // stage1: wave owns 128 h1 cols (C=8, R=1)
    f32x4 acc1[8];
    #pragma unroll
    for (int i = 0; i < 8; ++i) acc1[i] = z;
    #pragma unroll 1
    for (int k0 = 0; k0 < 16; ++k0) {
      int k2 = k0 * 4 + lg;
      s16x8 X = *(const s16x8*)((const char*)As + (k2 << 8) + (((l15 ^ (k2 & 15)) & 15) << 4));
      #pragma unroll
      for (int ci = 0; ci < 8; ++ci) {
        s16x8 W = *(const s16x8*)(w1p + (((wv * 8 + ci) * 16 + k0) << 9) + lane * 8);
        acc1[ci] = MFMA(W, X, acc1[ci]);
      }
    }
    #pragma unroll
    for (int ci = 0; ci < 8; ++ci) {
      f32x4 bv = *(const f32x4*)(b1 + wv * 128 + ci * 16 + lg * 4);
      int k2c = wv * 16 + ci * 2 + (lg >> 1);
      int half = (lg & 1) << 3;
      s16x4 o;
      #pragma unroll
      for (int j = 0; j < 4; ++j)
        o[j] = f2bf(fmaxf(acc1[ci][j] + bv[j], 0.f));
      *(s16x4*)((char*)h1s + (k2c << 8) + (l15 << 4) + half) = o;
    }
    __syncthreads();
    // stage2: wave owns 16 x2 cols, K=1024
    f32x4 acc2 = z;
    #pragma unroll 1
    for (int kk = 0; kk < 32; ++kk) {
      s16x8 X2 = *(const s16x8*)((const char*)h1s + ((kk * 4 + lg) << 8) + (l15 << 4));
      s16x8 W2 = *(const s16x8*)(w2p + (((wv * 32 + kk)) << 9) + lane * 8);
      acc2 = MFMA(W2, X2, acc2);
    }
    #pragma unroll
    for (int rr = 0; rr < 4; ++rr) {
      int d = wv * 16 + lg * 4 + rr;
      float v = fmaxf(acc2[rr] + b2[d], 0.f);
      out[3932160 + (((b * 16 + l15) * 7 + ti) << 7) + d] = v;
    }
    return;
  }

  // ===== fp8 enc main: 2 passes x 512 cols, C=4 x R=4 =====
  unsigned char* As8  = (unsigned char*)smem;
  unsigned char* h1q8 = (unsigned char*)(smem + 32768);
  const int rb = (blockIdx.x - 224) << 6;

  #pragma unroll
  for (int it = 0; it < 8; ++it) {
    int g = it * 512 + tid;
    int row = g >> 6, j = g & 63;
    const float* s = inp + (long)(rb + row) * 512 + j * 8;
    f32x4 v0 = *(const f32x4*)s;
    f32x4 v1 = *(const f32x4*)(s + 4);
    u64 pk = (u64)pk4e4(v0[0], v0[1], v0[2], v0[3])
           | ((u64)pk4e4(v1[0], v1[1], v1[2], v1[3]) << 32);
    *(u64*)(As8 + (j << 9) + ((row ^ (j & 15)) << 3)) = pk;
  }
  __syncthreads();

  f32x4 acc2[4] = {z, z, z, z};

  for (int p = 0; p < 2; ++p) {
    f32x4 acc1[4][4];
    #pragma unroll
    for (int i = 0; i < 4; ++i)
      #pragma unroll
      for (int j = 0; j < 4; ++j) acc1[i][j] = z;

    const unsigned char* wB = w1p8 + (((p * 32 + wv * 4) * 16) << 9) + lane * 8;

    i64 Wc[4];
    #pragma unroll
    for (int ci = 0; ci < 4; ++ci) Wc[ci] = *(const i64*)(wB + ((ci * 16) << 9));

    #pragma unroll 1
    for (int k0 = 0; k0 < 16; ++k0) {
      int kn = (k0 + 1) & 15;
      i64 Wn[4];
      #pragma unroll
      for (int ci = 0; ci < 4; ++ci) Wn[ci] = *(const i64*)(wB + ((ci * 16 + kn) << 9));
      int k2 = k0 * 4 + lg;
      int c = k2 & 15;
      i64 Xc[4];
      #pragma unroll
      for (int mi = 0; mi < 4; ++mi)
        Xc[mi] = *(const i64*)(As8 + (k2 << 9) + (((mi * 16 + l15) ^ c) << 3));
      #pragma unroll
      for (int ci = 0; ci < 4; ++ci)
        #pragma unroll
        for (int mi = 0; mi < 4; ++mi)
          acc1[ci][mi] = MFMA8(Wc[ci], Xc[mi], acc1[ci][mi]);
      #pragma unroll
      for (int ci = 0; ci < 4; ++ci) Wc[ci] = Wn[ci];
    }
    __syncthreads();  // prev pass's stage2 done reading h1q8
    // h1 write: e4m3 h1q8[k2c][m ^ (k2c&15)], 4B per (ci,mi)
    #pragma unroll
    for (int ci = 0; ci < 4; ++ci) {
      f32x4 bv = *(const f32x4*)(b1 + p * 512 + wv * 64 + ci * 16 + lg * 4);
      int k2c = wv * 8 + ci * 2 + (lg >> 1);
      int half = (lg & 1) << 2;
      #pragma unroll
      for (int mi = 0; mi < 4; ++mi) {
        int m = mi * 16 + l15;
        unsigned int pk = pk4e4(fmaxf(acc1[ci][mi][0] + bv[0], 0.f),
                                fmaxf(acc1[ci][mi][1] + bv[1], 0.f),
                                fmaxf(acc1[ci][mi][2] + bv[2], 0.f),
                                fmaxf(acc1[ci][mi][3] + bv[3], 0.f));
        *(unsigned int*)(h1q8 + (k2c << 9) + ((m ^ (k2c & 15)) << 3) + half) = pk;
      }
    }
    __syncthreads();
    // stage2: swizzled X2 reads
    const unsigned char* w2B = w2p8 + ((wv * 32 + p * 16) << 9) + lane * 8;
    i64 W2c = *(const i64*)(w2B);
    #pragma unroll 1
    for (int kk = 0; kk < 16; ++kk) {
      int kn = (kk + 1) & 15;
      i64 W2n = *(const i64*)(w2B + (kn << 9));
      int row = kk * 4 + lg;
      i64 X2[4];
      #pragma unroll
      for (int mi = 0; mi < 4; ++mi)
        X2[mi] = *(const i64*)(h1q8 + (row << 9) + (((mi * 16 + l15) ^ (row & 15)) << 3));
      #pragma unroll
      for (int mi = 0; mi < 4; ++mi)
        acc2[mi] = MFMA8(W2c, X2[mi], acc2[mi]);
      W2c = W2n;
    }
  }
  // epilogue: x2^T (relu+b2) -> e4m3 scratch (4-bit swizzle) -> fp8 seq
  __syncthreads();
  unsigned char* scr8 = As8;
  {
    f32x4 bv = *(const f32x4*)(b2 + wv * 16 + lg * 4);
    int gsb = wv * 2 + (lg >> 1);
    int off4 = (lg & 1) << 2;
    #pragma unroll
    for (int mi = 0; mi < 4; ++mi) {
      int m = mi * 16 + l15;
      int f15 = ((rb >> 4) + mi + 7) & 15;
      unsigned int pk = pk4e4(fmaxf(acc2[mi][0] + bv[0], 0.f),
                              fmaxf(acc2[mi][1] + bv[1], 0.f),
                              fmaxf(acc2[mi][2] + bv[2], 0.f),
                              fmaxf(acc2[mi][3] + bv[3], 0.f));
      int ls = (gsb ^ f15) ^ (m & 15);
      *(unsigned int*)(scr8 + m * 128 + ls * 8 + off4) = pk;
    }
  }
  __syncthreads();
  #pragma unroll
  for (int it = 0; it < 2; ++it) {
    int c = it * 512 + tid;
    int i = c >> 4, s = c & 15;
    u64 v = *(const u64*)(scr8 + i * 128 + ((s ^ (i & 15)) << 3));
    int r = rb + i;
    int ba2 = ((r >> 12) << 4) + (r & 15);
    int t = (r >> 4) & 255;
    int f = t + 7;
    *(u64*)(seq8 + (ba2 * SEQ_T + f) * 128 + (s << 3)) = v;
  }
}

// ---------------- fp8 sliding-window GEMM: h3 = relu(wins@w3+b3) -> fp8 dec A-frags ----------------
__global__ __launch_bounds__(512, 4) void win_kernel(
    const unsigned char* __restrict__ seq8, const unsigned char* __restrict__ w3p8,
    const float* __restrict__ b3, unsigned char* __restrict__ h3p8)
{
  __shared__ unsigned char sh8[17280] __attribute__((aligned(16)));  // 135 frames x 128B
  __shared__ short rp[8192] __attribute__((aligned(16)));            // 128 x 64 bf16 (16KB)
  const int tid = threadIdx.x;
  const int lane = tid & 63, wid = tid >> 6;
  const int wm = wid >> 2, wn = wid & 3;
  const int l15 = lane & 15, lg = lane >> 4;
  const int bid = blockIdx.x;
  const int th = bid & 1, ba = bid >> 1;
  const int t0 = th << 7;

  const unsigned char* gsrc = seq8 + (ba * SEQ_T + t0) * 128;
  #pragma unroll
  for (int i = 0; i < 3; ++i) {
    int c = i * 512 + tid;
    if (c < 1080) *(s16x8*)&sh8[c * 16] = *(const s16x8*)(gsrc + c * 16);
  }
  __syncthreads();

  f32x4 z = {0.f, 0.f, 0.f, 0.f};
  for (int h = 0; h < 2; ++h) {
    f32x4 acc[4][4];
    #pragma unroll
    for (int i = 0; i < 4; ++i)
      #pragma unroll
      for (int j = 0; j < 4; ++j) acc[i][j] = z;

    const unsigned char* bB = w3p8 + (((h * 16 + wn * 4) * 32) << 9) + lane * 8;
    i64 bcur[4];
    #pragma unroll
    for (int nf = 0; nf < 4; ++nf) bcur[nf] = *(const i64*)(bB + ((nf * 32) << 9));

    #pragma unroll 1
    for (int kc = 0; kc < 32; ++kc) {
      int kn = (kc + 1) & 31;
      i64 bnxt[4];
      #pragma unroll
      for (int nf = 0; nf < 4; ++nf) bnxt[nf] = *(const i64*)(bB + ((nf * 32 + kn) << 9));
      int w = kc >> 2;
      int dslot = ((kc & 3) << 2) + lg;
      i64 av[4];
      #pragma unroll
      for (int mf = 0; mf < 4; ++mf) {
        int f = wm * 64 + mf * 16 + l15 + w;
        av[mf] = *(const i64*)(sh8 + f * 128 + ((dslot ^ (f & 15)) << 3));
      }
      #pragma unroll
      for (int nf = 0; nf < 4; ++nf)
        #pragma unroll
        for (int mf = 0; mf < 4; ++mf)
          acc[mf][nf] = MFMA8(av[mf], bcur[nf], acc[mf][nf]);
      #pragma unroll
      for (int nf = 0; nf < 4; ++nf) bcur[nf] = bnxt[nf];
    }

    // epilogue: 4 sub-passes of 64 cols (nf = s)
    for (int s = 0; s < 4; ++s) {
      __syncthreads();
      #pragma unroll
      for (int mf = 0; mf < 4; ++mf) {
        float bias = b3[h * 256 + wn * 64 + s * 16 + l15];
        int lc = wn * 16 + l15;
        #pragma unroll
        for (int rr = 0; rr < 4; ++rr) {
          int row = wm * 64 + mf * 16 + lg * 4 + rr;
          float v = fmaxf(acc[mf][s][rr] + bias, 0.f);
          int by = ((row << 7) + (lc << 1)) ^ ((row & 7) << 4);
          rp[by >> 1] = f2bf(v);
        }
      }
      __syncthreads();
      #pragma unroll
      for (int it = 0; it < 2; ++it) {
        int c = it * 512 + tid;
        int cl = c & 15, qh = (c >> 4) & 1, wnl = (c >> 5) & 3, tt = (c >> 7) & 7;
        int row = tt * 16 + cl;
        int qb = wnl * 16 + qh * 8;
        int by = ((row << 7) + (qb << 1)) ^ ((row & 7) << 4);
        s16x8 v = *(const s16x8*)((const char*)rp + by);
        u64 pk = (u64)pk4e4(bf2f(v[0]), bf2f(v[1]), bf2f(v[2]), bf2f(v[3]))
               | ((u64)pk4e4(bf2f(v[4]), bf2f(v[5]), bf2f(v[6]), bf2f(v[7])) << 32);
        int k0g = h * 8 + wnl * 2 + (s >> 1);
        int g = ((s & 1) << 1) + qh;
        int mt = ba * 16 + th * 8 + tt;
        long dst = ((long)((mt * 16 + k0g) * 64 + g * 16 + cl)) << 3;
        *(u64*)(h3p8 + dst) = pk;
      }
    }
  }
}

// ---------------- decoder: q = relu(h3@w4+b4)@w5+b5 (stage4 fp8, stage5 bf16) ----------------
__global__ __launch_bounds__(512, 4) void dec_kernel(
    const unsigned char* __restrict__ h3p8, const unsigned char* __restrict__ w4p8,
    const float* __restrict__ b4, const short* __restrict__ w5p,
    const float* __restrict__ b5, float* __restrict__ out)
{
  __shared__ short h4s[32768] __attribute__((aligned(16)));
  const int tid = threadIdx.x;
  const int lane = tid & 63, wid = tid >> 6;
  const int wm = wid >> 2, wn = wid & 3;
  const int mf5 = wid;
  const int l15 = lane & 15, lg = lane >> 4;
  const int rb = blockIdx.x << 7;

  f32x4 z = {0.f, 0.f, 0.f, 0.f};
  f32x4 acc5[2] = {z, z};
  const unsigned char* aBase = h3p8 + (long)((rb >> 4) + wm * 4) * 8192 + lane * 8;

  for (int h = 0; h < 2; ++h) {
    f32x4 acc[4][4];
    #pragma unroll
    for (int i = 0; i < 4; ++i)
      #pragma unroll
      for (int j = 0; j < 4; ++j) acc[i][j] = z;

    const unsigned char* bB = w4p8 + (((h * 16 + wn * 4) * 16) << 9) + lane * 8;
    i64 bcur[4];
    #pragma unroll
    for (int nf = 0; nf < 4; ++nf) bcur[nf] = *(const i64*)(bB + ((nf * 16) << 9));

    #pragma unroll 1
    for (int k0 = 0; k0 < 16; ++k0) {
      int kn = (k0 + 1) & 15;
      i64 bnxt[4];
      #pragma unroll
      for (int nf = 0; nf < 4; ++nf) bnxt[nf] = *(const i64*)(bB + ((nf * 16 + kn) << 9));
      i64 av[4];
      #pragma unroll
      for (int mf = 0; mf < 4; ++mf) av[mf] = *(const i64*)(aBase + mf * 8192 + k0 * 512);
      #pragma unroll
      for (int nf = 0; nf < 4; ++nf)
        #pragma unroll
        for (int mf = 0; mf < 4; ++mf)
          acc[mf][nf] = MFMA8(av[mf], bcur[nf], acc[mf][nf]);
      #pragma unroll
      for (int nf = 0; nf < 4; ++nf) bcur[nf] = bnxt[nf];
    }
    __syncthreads();
    #pragma unroll
    for (int mf = 0; mf < 4; ++mf)
      #pragma unroll
      for (int nf = 0; nf < 4; ++nf) {
        int lc = wn * 64 + nf * 16 + l15;
        float bias = b4[h * 256 + lc];
        #pragma unroll
        for (int rr = 0; rr < 4; ++rr) {
          int row = wm * 64 + mf * 16 + lg * 4 + rr;
          float v = fmaxf(acc[mf][nf][rr] + bias, 0.f);
          int by = ((row << 9) + (lc << 1)) ^ ((row & 15) << 4);
          h4s[by >> 1] = f2bf(v);
        }
      }
    __syncthreads();
    #pragma unroll
    for (int kk = 0; kk < 8; ++kk) {
      int row = mf5 * 16 + l15;
      int by = ((row << 9) + (kk << 6) + (lg << 4)) ^ ((row & 15) << 4);
      s16x8 a0 = *(const s16x8*)((const char*)h4s + by);
      #pragma unroll
      for (int nf = 0; nf < 2; ++nf) {
        s16x8 wb = *(const s16x8*)(w5p + (nf * 16 + h * 8 + kk) * 512 + lane * 8);
        acc5[nf] = MFMA(a0, wb, acc5[nf]);
      }
    }
  }
  #pragma unroll
  for (int nf = 0; nf < 2; ++nf) {
    int col = nf * 16 + l15;
    if (col < 30) {
      float bias = b5[col];
      #pragma unroll
      for (int rr = 0; rr < 4; ++rr) {
        int row_ = rb + mf5 * 16 + lg * 4 + rr;
        int t = row_ & 255;
        int ba2 = row_ >> 8;
        int orow = (((ba2 >> 4) << 8) + t) * 16 + (ba2 & 15);
        out[orow * 30 + col] = acc5[nf][rr] + bias;
      }
    }
  }
}

extern "C" void kernel_launch(void* const* d_in, const int* in_sizes, int n_in,
                              void* d_out, int out_size, void* d_ws, size_t ws_size,
                              hipStream_t stream) {
  const float* inp = (const float*)d_in[0];
  const float* hid = (const float*)d_in[1];
  const float* w1  = (const float*)d_in[2];
  const float* b1  = (const float*)d_in[3];
  const float* w2  = (const float*)d_in[4];
  const float* b2  = (const float*)d_in[5];
  const float* w3  = (const float*)d_in[6];
  const float* b3  = (const float*)d_in[7];
  const float* w4  = (const float*)d_in[8];
  const float* b4  = (const float*)d_in[9];
  const float* w5  = (const float*)d_in[10];
  const float* b5  = (const float*)d_in[11];

  char* ws = (char*)d_ws;
  short* wp   = (short*)ws;
  short* w1p  = wp;
  short* w2p  = wp + W2P_OFF;
  short* w5p  = wp + W5P_OFF;
  unsigned char* w3p8 = (unsigned char*)(ws + W3P8_BYTE_OFF);
  unsigned char* seq8 = (unsigned char*)(ws + SEQ8_BYTE_OFF);
  unsigned char* w4p8 = (unsigned char*)(ws + W4P8_BYTE_OFF);
  unsigned char* h3p8 = (unsigned char*)(ws + BIG_BYTE_OFF);
  unsigned char* w1p8 = h3p8;               // dead once win writes h3p8 (after enc)
  unsigned char* w2p8 = w1p8 + 524288;
  float* out  = (float*)d_out;

  prep_kernel <<<3552, 256, 0, stream>>>(w1, w2, w3, w4, w5, hid,
                                         wp, w1p8, w3p8, w4p8, seq8);
  enc_kernel  <<<2272, 512, 0, stream>>>(inp, w1p8, b1, w2p8, b2, seq8,
                                         w1p, w2p, out);
  win_kernel  <<<1024, 512, 0, stream>>>(seq8, w3p8, b3, h3p8);
  dec_kernel  <<<1024, 512, 0, stream>>>(h3p8, w4p8, b4, w5p, b5, out);
}

// Round 16
// 387.887 us; speedup vs baseline: 1.0128x; 1.0128x over previous
//
#include <hip/hip_runtime.h>
#include <hip/hip_bf16.h>
#include <hip/hip_fp8.h>

// SlidingFFAgent: fused 5-layer MLP + sliding window, MFMA pipeline.
// Round 16: r14 structure restored (best); enc gains depth-2 W prefetch
// (named-register rotation, stage1+stage2). Everything else = r14.

#define DEVI __device__ __forceinline__

typedef float f32x4 __attribute__((ext_vector_type(4)));
typedef short s16x8 __attribute__((ext_vector_type(8)));
typedef short s16x4 __attribute__((ext_vector_type(4)));
typedef long long i64;
typedef unsigned long long u64;

#define ROWS 131072
#define SEQ_T 263

// packed bf16 weight offsets (in shorts)
#define W2P_OFF 524288
#define W5P_OFF 1441792

#define W3P8_BYTE_OFF 2916352           // fp8 w3 frags (512KB)
#define SEQ8_BYTE_OFF 3440640           // fp8 seq: 512 ba x 263 x 128B
#define W4P8_BYTE_OFF 20971520          // fp8 w4 frags (256KB)
#define BIG_BYTE_OFF 37388288           // h3p8; head doubles as fp8 w1/w2 for enc

DEVI short f2bf(float f) {
  union { __hip_bfloat16 h; short s; } u;
  u.h = __float2bfloat16(f);
  return u.s;
}
DEVI float bf2f(short s) {
  union { float f; unsigned int u; } v;
  v.u = ((unsigned int)(unsigned short)s) << 16;
  return v.f;
}

DEVI unsigned int f2e4(float f) {
  union { __hip_fp8_e4m3 h; unsigned char c; } u;
  u.h = __hip_fp8_e4m3(f);
  return (unsigned int)u.c;
}

#if __has_builtin(__builtin_amdgcn_cvt_pk_fp8_f32)
DEVI unsigned int pk4e4(float a, float b, float c, float d) {
  int v = 0;
  v = __builtin_amdgcn_cvt_pk_fp8_f32(a, b, v, false);
  v = __builtin_amdgcn_cvt_pk_fp8_f32(c, d, v, true);
  return (unsigned int)v;
}
#else
DEVI unsigned int pk4e4(float a, float b, float c, float d) {
  return f2e4(a) | (f2e4(b) << 8) | (f2e4(c) << 16) | (f2e4(d) << 24);
}
#endif

DEVI f32x4 MFMA(s16x8 a, s16x8 b, f32x4 c) {
  return __builtin_amdgcn_mfma_f32_16x16x32_bf16(a, b, c, 0, 0, 0);
}
DEVI f32x4 MFMA8(i64 a, i64 b, f32x4 c) {
  return __builtin_amdgcn_mfma_f32_16x16x32_fp8_fp8(a, b, c, 0, 0, 0);
}

// ---------------- merged prep: bf16 packs (w1/w2/w5) + fp8 packs (w1..w4) + hid ----------------
__global__ __launch_bounds__(256) void prep_kernel(
    const float* __restrict__ w1, const float* __restrict__ w2,
    const float* __restrict__ w3, const float* __restrict__ w4,
    const float* __restrict__ w5, const float* __restrict__ hid,
    short* __restrict__ wp, unsigned char* __restrict__ wp8,
    unsigned char* __restrict__ w3p8, unsigned char* __restrict__ w4p8,
    unsigned char* __restrict__ seq8)
{
  int t0 = blockIdx.x * 256 + threadIdx.x;
  if (t0 < 671744) {
    int idx = t0;
    const float* src; int sh, Nsrc, local; long dsto;
    if (idx < W2P_OFF)     { src = w1; sh = 4; Nsrc = 1024; local = idx;           dsto = idx; }
    else if (idx < 655360) { src = w2; sh = 5; Nsrc = 128;  local = idx - W2P_OFF; dsto = idx; }
    else                   { src = w5; sh = 4; Nsrc = 30;   local = idx - 655360;  dsto = W5P_OFF + (idx - 655360); }
    int j    = local & 7;
    int lane = (local >> 3) & 63;
    int rest = local >> 9;
    int k0   = rest & ((1 << sh) - 1);
    int n0   = rest >> sh;
    int k = (k0 << 5) + ((lane >> 4) << 3) + j;
    int n = (n0 << 4) + (lane & 15);
    float v = (n < Nsrc) ? src[k * Nsrc + n] : 0.f;
    wp[dsto] = f2bf(v);
  } else if (t0 < 851968) {
    int t = t0 - 671744;
    const float* src; int nkshift, Nsrc, dt; unsigned char* dst;
    if (t < 65536)       { src = w1; dt = t;          nkshift = 4; Nsrc = 1024; dst = wp8; }
    else if (t < 81920)  { src = w2; dt = t - 65536;  nkshift = 5; Nsrc = 128;  dst = wp8 + 524288; }
    else if (t < 147456) { src = w3; dt = t - 81920;  nkshift = 5; Nsrc = 512;  dst = w3p8; }
    else                 { src = w4; dt = t - 147456; nkshift = 4; Nsrc = 512;  dst = w4p8; }
    int lane = dt & 63;
    int rest = dt >> 6;
    int k0   = rest & ((1 << nkshift) - 1);
    int n0   = rest >> nkshift;
    int kb = (k0 << 5) + ((lane >> 4) << 3);
    int n  = (n0 << 4) + (lane & 15);
    float v[8];
    #pragma unroll
    for (int j = 0; j < 8; ++j) v[j] = src[(kb + j) * Nsrc + n];
    u64 pk = (u64)pk4e4(v[0], v[1], v[2], v[3])
           | ((u64)pk4e4(v[4], v[5], v[6], v[7]) << 32);
    *(u64*)(dst + (long)dt * 8) = pk;
  } else {
    int t = t0 - 851968;   // 57344 total
    int j = t & 15;
    int r = t >> 4;
    int i = r % 7;
    int ba = r / 7;
    int s = j ^ i;
    const float* src = hid + (r << 7) + (j << 3);
    f32x4 a = *(const f32x4*)src;
    f32x4 b = *(const f32x4*)(src + 4);
    u64 pk = (u64)pk4e4(a[0], a[1], a[2], a[3])
           | ((u64)pk4e4(b[0], b[1], b[2], b[3]) << 32);
    *(u64*)(seq8 + (ba * SEQ_T + i) * 128 + s * 8) = pk;
  }
}

// ---------------- fp8 encoder: 2 passes x 512 cols, C=4 x R=4, depth-2 W prefetch ----------------
__global__ __launch_bounds__(512, 4) void enc_kernel(
    const float* __restrict__ inp, const unsigned char* __restrict__ w1p8,
    const float* __restrict__ b1, const unsigned char* __restrict__ w2p8,
    const float* __restrict__ b2, unsigned char* __restrict__ seq8)
{
  __shared__ unsigned char As8[32768] __attribute__((aligned(16)));
  __shared__ unsigned char h1q8[32768] __attribute__((aligned(16)));
  const int tid = threadIdx.x;
  const int lane = tid & 63, wv = tid >> 6;     // wave 0..7
  const int l15 = lane & 15, lg = lane >> 4;
  const int rb = blockIdx.x << 6;

  // ---- stage A: f32 rows -> e4m3 LDS [k2 64][m 64], 4-bit swizzle ----
  #pragma unroll
  for (int it = 0; it < 8; ++it) {
    int g = it * 512 + tid;
    int row = g >> 6, j = g & 63;
    const float* s = inp + (long)(rb + row) * 512 + j * 8;
    f32x4 v0 = *(const f32x4*)s;
    f32x4 v1 = *(const f32x4*)(s + 4);
    u64 pk = (u64)pk4e4(v0[0], v0[1], v0[2], v0[3])
           | ((u64)pk4e4(v1[0], v1[1], v1[2], v1[3]) << 32);
    *(u64*)(As8 + (j << 9) + ((row ^ (j & 15)) << 3)) = pk;
  }
  __syncthreads();

  f32x4 z = {0.f, 0.f, 0.f, 0.f};
  f32x4 acc2[4] = {z, z, z, z};

  for (int p = 0; p < 2; ++p) {
    // ---- stage 1: h1^T cols [p*512 + wv*64, +64), C=4 x R=4, W depth-2 ----
    f32x4 acc1[4][4];
    #pragma unroll
    for (int i = 0; i < 4; ++i)
      #pragma unroll
      for (int j = 0; j < 4; ++j) acc1[i][j] = z;

    const unsigned char* wB = w1p8 + (((p * 32 + wv * 4) * 16) << 9) + lane * 8;

    i64 Wc[4], Wn[4];
    #pragma unroll
    for (int ci = 0; ci < 4; ++ci) {
      Wc[ci] = *(const i64*)(wB + ((ci * 16 + 0) << 9));
      Wn[ci] = *(const i64*)(wB + ((ci * 16 + 1) << 9));
    }

    #pragma unroll 1
    for (int k0 = 0; k0 < 16; ++k0) {
      int kn2 = (k0 + 2) & 15;
      i64 Wn2[4];
      #pragma unroll
      for (int ci = 0; ci < 4; ++ci) Wn2[ci] = *(const i64*)(wB + ((ci * 16 + kn2) << 9));
      int k2 = k0 * 4 + lg;
      int c = k2 & 15;
      i64 Xc[4];
      #pragma unroll
      for (int mi = 0; mi < 4; ++mi)
        Xc[mi] = *(const i64*)(As8 + (k2 << 9) + (((mi * 16 + l15) ^ c) << 3));
      #pragma unroll
      for (int ci = 0; ci < 4; ++ci)
        #pragma unroll
        for (int mi = 0; mi < 4; ++mi)
          acc1[ci][mi] = MFMA8(Wc[ci], Xc[mi], acc1[ci][mi]);
      #pragma unroll
      for (int ci = 0; ci < 4; ++ci) { Wc[ci] = Wn[ci]; Wn[ci] = Wn2[ci]; }
    }
    __syncthreads();  // prev pass's stage2 done reading h1q8
    // ---- write h1^T (relu+b1) -> e4m3 h1q8[k2c][m], 4B per (ci,mi) ----
    #pragma unroll
    for (int ci = 0; ci < 4; ++ci) {
      f32x4 bv = *(const f32x4*)(b1 + p * 512 + wv * 64 + ci * 16 + lg * 4);
      int k2c = wv * 8 + ci * 2 + (lg >> 1);
      int half = (lg & 1) << 2;
      #pragma unroll
      for (int mi = 0; mi < 4; ++mi) {
        int m = mi * 16 + l15;
        unsigned int pk = pk4e4(fmaxf(acc1[ci][mi][0] + bv[0], 0.f),
                                fmaxf(acc1[ci][mi][1] + bv[1], 0.f),
                                fmaxf(acc1[ci][mi][2] + bv[2], 0.f),
                                fmaxf(acc1[ci][mi][3] + bv[3], 0.f));
        *(unsigned int*)(h1q8 + (k2c << 9) + (m << 3) + half) = pk;
      }
    }
    __syncthreads();
    // ---- stage 2: acc2 += mfma(w2frag, h1frag), 16 k-steps, W depth-2 ----
    const unsigned char* w2B = w2p8 + ((wv * 32 + p * 16) << 9) + lane * 8;
    i64 W2c = *(const i64*)(w2B);
    i64 W2n = *(const i64*)(w2B + (1 << 9));
    #pragma unroll 1
    for (int kk = 0; kk < 16; ++kk) {
      int kn2 = (kk + 2) & 15;
      i64 W2n2 = *(const i64*)(w2B + (kn2 << 9));
      i64 X2[4];
      #pragma unroll
      for (int mi = 0; mi < 4; ++mi)
        X2[mi] = *(const i64*)(h1q8 + ((kk * 4 + lg) << 9) + ((mi * 16 + l15) << 3));
      #pragma unroll
      for (int mi = 0; mi < 4; ++mi)
        acc2[mi] = MFMA8(W2c, X2[mi], acc2[mi]);
      W2c = W2n; W2n = W2n2;
    }
  }
  // ---- epilogue: x2^T (relu+b2) -> e4m3 scratch (4-bit swizzle) -> fp8 seq ----
  __syncthreads();
  unsigned char* scr8 = As8;
  {
    f32x4 bv = *(const f32x4*)(b2 + wv * 16 + lg * 4);
    int gsb = wv * 2 + (lg >> 1);
    int off4 = (lg & 1) << 2;
    #pragma unroll
    for (int mi = 0; mi < 4; ++mi) {
      int m = mi * 16 + l15;
      int f15 = ((rb >> 4) + mi + 7) & 15;
      unsigned int pk = pk4e4(fmaxf(acc2[mi][0] + bv[0], 0.f),
                              fmaxf(acc2[mi][1] + bv[1], 0.f),
                              fmaxf(acc2[mi][2] + bv[2], 0.f),
                              fmaxf(acc2[mi][3] + bv[3], 0.f));
      int ls = (gsb ^ f15) ^ (m & 15);
      *(unsigned int*)(scr8 + m * 128 + ls * 8 + off4) = pk;
    }
  }
  __syncthreads();
  #pragma unroll
  for (int it = 0; it < 2; ++it) {
    int c = it * 512 + tid;
    int i = c >> 4, s = c & 15;
    u64 v = *(const u64*)(scr8 + i * 128 + ((s ^ (i & 15)) << 3));
    int r = rb + i;
    int ba2 = ((r >> 12) << 4) + (r & 15);
    int t = (r >> 4) & 255;
    int f = t + 7;
    *(u64*)(seq8 + (ba2 * SEQ_T + f) * 128 + (s << 3)) = v;
  }
}

// ---------------- bf16 recompute of window frames (t=249..255) -> output 1 ----------------
__global__ __launch_bounds__(256) void enc_hi_kernel(
    const float* __restrict__ inp, const short* __restrict__ w1p,
    const float* __restrict__ b1, const short* __restrict__ w2p,
    const float* __restrict__ b2, float* __restrict__ out)
{
  __shared__ short As[8192]  __attribute__((aligned(16)));
  __shared__ short h1s[16384] __attribute__((aligned(16)));
  const int tid = threadIdx.x;
  const int lane = tid & 63, wv = tid >> 6;
  const int l15 = lane & 15, lg = lane >> 4;
  const int b = blockIdx.x / 7, ti = blockIdx.x % 7;
  const int t = 249 + ti;
  const long row0 = (long)b * 4096 + t * 16;

  #pragma unroll
  for (int it = 0; it < 4; ++it) {
    int c = it * 256 + tid;
    int m = c >> 6, j = c & 63;
    const float* s = inp + (row0 + m) * 512 + j * 8;
    f32x4 v0 = *(const f32x4*)s;
    f32x4 v1 = *(const f32x4*)(s + 4);
    s16x8 o;
    o[0]=f2bf(v0[0]); o[1]=f2bf(v0[1]); o[2]=f2bf(v0[2]); o[3]=f2bf(v0[3]);
    o[4]=f2bf(v1[0]); o[5]=f2bf(v1[1]); o[6]=f2bf(v1[2]); o[7]=f2bf(v1[3]);
    *(s16x8*)((char*)As + (j << 8) + (((m ^ (j & 15)) & 15) << 4)) = o;
  }
  __syncthreads();

  f32x4 z = {0.f, 0.f, 0.f, 0.f};
  f32x4 acc1[16];
  #pragma unroll
  for (int i = 0; i < 16; ++i) acc1[i] = z;
  #pragma unroll 1
  for (int k0 = 0; k0 < 16; ++k0) {
    int k2 = k0 * 4 + lg;
    s16x8 X = *(const s16x8*)((const char*)As + (k2 << 8) + (((l15 ^ (k2 & 15)) & 15) << 4));
    #pragma unroll
    for (int ci = 0; ci < 16; ++ci) {
      s16x8 W = *(const s16x8*)(w1p + (((wv * 16 + ci) * 16 + k0) << 9) + lane * 8);
      acc1[ci] = MFMA(W, X, acc1[ci]);
    }
  }
  #pragma unroll
  for (int ci = 0; ci < 16; ++ci) {
    f32x4 bv = *(const f32x4*)(b1 + wv * 256 + ci * 16 + lg * 4);
    int k2c = wv * 32 + ci * 2 + (lg >> 1);
    int half = (lg & 1) << 3;
    s16x4 o;
    #pragma unroll
    for (int j = 0; j < 4; ++j)
      o[j] = f2bf(fmaxf(acc1[ci][j] + bv[j], 0.f));
    *(s16x4*)((char*)h1s + (k2c << 8) + (l15 << 4) + half) = o;
  }
  __syncthreads();
  f32x4 acc2[2] = {z, z};
  #pragma unroll 1
  for (int kk = 0; kk < 32; ++kk) {
    s16x8 X2 = *(const s16x8*)((const char*)h1s + ((kk * 4 + lg) << 8) + (l15 << 4));
    #pragma unroll
    for (int nf = 0; nf < 2; ++nf) {
      s16x8 W2 = *(const s16x8*)(w2p + (((wv * 2 + nf) * 32 + kk) << 9) + lane * 8);
      acc2[nf] = MFMA(W2, X2, acc2[nf]);
    }
  }
  #pragma unroll
  for (int nf = 0; nf < 2; ++nf) {
    #pragma unroll
    for (int rr = 0; rr < 4; ++rr) {
      int d = (wv * 2 + nf) * 16 + lg * 4 + rr;
      float v = fmaxf(acc2[nf][rr] + b2[d], 0.f);
      out[3932160 + (((b * 16 + l15) * 7 + ti) << 7) + d] = v;
    }
  }
}

// ---------------- fp8 sliding-window GEMM: h3 = relu(wins@w3+b3) -> fp8 dec A-frags ----------------
__global__ __launch_bounds__(512, 4) void win_kernel(
    const unsigned char* __restrict__ seq8, const unsigned char* __restrict__ w3p8,
    const float* __restrict__ b3, unsigned char* __restrict__ h3p8)
{
  __shared__ unsigned char sh8[17280] __attribute__((aligned(16)));  // 135 frames x 128B
  __shared__ short rp[8192] __attribute__((aligned(16)));            // 128 x 64 bf16 (16KB)
  const int tid = threadIdx.x;
  const int lane = tid & 63, wid = tid >> 6;
  const int wm = wid >> 2, wn = wid & 3;
  const int l15 = lane & 15, lg = lane >> 4;
  const int bid = blockIdx.x;
  const int th = bid & 1, ba = bid >> 1;
  const int t0 = th << 7;

  const unsigned char* gsrc = seq8 + (ba * SEQ_T + t0) * 128;
  #pragma unroll
  for (int i = 0; i < 3; ++i) {
    int c = i * 512 + tid;
    if (c < 1080) *(s16x8*)&sh8[c * 16] = *(const s16x8*)(gsrc + c * 16);
  }
  __syncthreads();

  f32x4 z = {0.f, 0.f, 0.f, 0.f};
  for (int h = 0; h < 2; ++h) {
    f32x4 acc[4][4];
    #pragma unroll
    for (int i = 0; i < 4; ++i)
      #pragma unroll
      for (int j = 0; j < 4; ++j) acc[i][j] = z;

    const unsigned char* bB = w3p8 + (((h * 16 + wn * 4) * 32) << 9) + lane * 8;
    i64 bcur[4];
    #pragma unroll
    for (int nf = 0; nf < 4; ++nf) bcur[nf] = *(const i64*)(bB + ((nf * 32) << 9));

    #pragma unroll 1
    for (int kc = 0; kc < 32; ++kc) {
      int kn = (kc + 1) & 31;
      i64 bnxt[4];
      #pragma unroll
      for (int nf = 0; nf < 4; ++nf) bnxt[nf] = *(const i64*)(bB + ((nf * 32 + kn) << 9));
      int w = kc >> 2;
      int dslot = ((kc & 3) << 2) + lg;
      i64 av[4];
      #pragma unroll
      for (int mf = 0; mf < 4; ++mf) {
        int f = wm * 64 + mf * 16 + l15 + w;
        av[mf] = *(const i64*)(sh8 + f * 128 + ((dslot ^ (f & 15)) << 3));
      }
      #pragma unroll
      for (int nf = 0; nf < 4; ++nf)
        #pragma unroll
        for (int mf = 0; mf < 4; ++mf)
          acc[mf][nf] = MFMA8(av[mf], bcur[nf], acc[mf][nf]);
      #pragma unroll
      for (int nf = 0; nf < 4; ++nf) bcur[nf] = bnxt[nf];
    }

    // epilogue: 4 sub-passes of 64 cols (nf = s)
    for (int s = 0; s < 4; ++s) {
      __syncthreads();
      #pragma unroll
      for (int mf = 0; mf < 4; ++mf) {
        float bias = b3[h * 256 + wn * 64 + s * 16 + l15];
        int lc = wn * 16 + l15;
        #pragma unroll
        for (int rr = 0; rr < 4; ++rr) {
          int row = wm * 64 + mf * 16 + lg * 4 + rr;
          float v = fmaxf(acc[mf][s][rr] + bias, 0.f);
          int by = ((row << 7) + (lc << 1)) ^ ((row & 7) << 4);
          rp[by >> 1] = f2bf(v);
        }
      }
      __syncthreads();
      #pragma unroll
      for (int it = 0; it < 2; ++it) {
        int c = it * 512 + tid;
        int cl = c & 15, qh = (c >> 4) & 1, wnl = (c >> 5) & 3, tt = (c >> 7) & 7;
        int row = tt * 16 + cl;
        int qb = wnl * 16 + qh * 8;
        int by = ((row << 7) + (qb << 1)) ^ ((row & 7) << 4);
        s16x8 v = *(const s16x8*)((const char*)rp + by);
        u64 pk = (u64)pk4e4(bf2f(v[0]), bf2f(v[1]), bf2f(v[2]), bf2f(v[3]))
               | ((u64)pk4e4(bf2f(v[4]), bf2f(v[5]), bf2f(v[6]), bf2f(v[7])) << 32);
        int k0g = h * 8 + wnl * 2 + (s >> 1);
        int g = ((s & 1) << 1) + qh;
        int mt = ba * 16 + th * 8 + tt;
        long dst = ((long)((mt * 16 + k0g) * 64 + g * 16 + cl)) << 3;
        *(u64*)(h3p8 + dst) = pk;
      }
    }
  }
}

// ---------------- decoder: q = relu(h3@w4+b4)@w5+b5 (stage4 fp8, stage5 bf16) ----------------
__global__ __launch_bounds__(512, 4) void dec_kernel(
    const unsigned char* __restrict__ h3p8, const unsigned char* __restrict__ w4p8,
    const float* __restrict__ b4, const short* __restrict__ w5p,
    const float* __restrict__ b5, float* __restrict__ out)
{
  __shared__ short h4s[32768] __attribute__((aligned(16)));
  const int tid = threadIdx.x;
  const int lane = tid & 63, wid = tid >> 6;
  const int wm = wid >> 2, wn = wid & 3;
  const int mf5 = wid;
  const int l15 = lane & 15, lg = lane >> 4;
  const int rb = blockIdx.x << 7;

  f32x4 z = {0.f, 0.f, 0.f, 0.f};
  f32x4 acc5[2] = {z, z};
  const unsigned char* aBase = h3p8 + (long)((rb >> 4) + wm * 4) * 8192 + lane * 8;

  for (int h = 0; h < 2; ++h) {
    f32x4 acc[4][4];
    #pragma unroll
    for (int i = 0; i < 4; ++i)
      #pragma unroll
      for (int j = 0; j < 4; ++j) acc[i][j] = z;

    const unsigned char* bB = w4p8 + (((h * 16 + wn * 4) * 16) << 9) + lane * 8;
    i64 bcur[4];
    #pragma unroll
    for (int nf = 0; nf < 4; ++nf) bcur[nf] = *(const i64*)(bB + ((nf * 16) << 9));

    #pragma unroll 1
    for (int k0 = 0; k0 < 16; ++k0) {
      int kn = (k0 + 1) & 15;
      i64 bnxt[4];
      #pragma unroll
      for (int nf = 0; nf < 4; ++nf) bnxt[nf] = *(const i64*)(bB + ((nf * 16 + kn) << 9));
      i64 av[4];
      #pragma unroll
      for (int mf = 0; mf < 4; ++mf) av[mf] = *(const i64*)(aBase + mf * 8192 + k0 * 512);
      #pragma unroll
      for (int nf = 0; nf < 4; ++nf)
        #pragma unroll
        for (int mf = 0; mf < 4; ++mf)
          acc[mf][nf] = MFMA8(av[mf], bcur[nf], acc[mf][nf]);
      #pragma unroll
      for (int nf = 0; nf < 4; ++nf) bcur[nf] = bnxt[nf];
    }
    __syncthreads();
    #pragma unroll
    for (int mf = 0; mf < 4; ++mf)
      #pragma unroll
      for (int nf = 0; nf < 4; ++nf) {
        int lc = wn * 64 + nf * 16 + l15;
        float bias = b4[h * 256 + lc];
        #pragma unroll
        for (int rr = 0; rr < 4; ++rr) {
          int row = wm * 64 + mf * 16 + lg * 4 + rr;
          float v = fmaxf(acc[mf][nf][rr] + bias, 0.f);
          int by = ((row << 9) + (lc << 1)) ^ ((row & 7) << 4);
          h4s[by >> 1] = f2bf(v);
        }
      }
    __syncthreads();
    #pragma unroll
    for (int kk = 0; kk < 8; ++kk) {
      int row = mf5 * 16 + l15;
      int by = ((row << 9) + (kk << 6) + (lg << 4)) ^ ((row & 7) << 4);
      s16x8 a0 = *(const s16x8*)((const char*)h4s + by);
      #pragma unroll
      for (int nf = 0; nf < 2; ++nf) {
        s16x8 wb = *(const s16x8*)(w5p + (nf * 16 + h * 8 + kk) * 512 + lane * 8);
        acc5[nf] = MFMA(a0, wb, acc5[nf]);
      }
    }
  }
  #pragma unroll
  for (int nf = 0; nf < 2; ++nf) {
    int col = nf * 16 + l15;
    if (col < 30) {
      float bias = b5[col];
      #pragma unroll
      for (int rr = 0; rr < 4; ++rr) {
        int row_ = rb + mf5 * 16 + lg * 4 + rr;
        int t = row_ & 255;
        int ba2 = row_ >> 8;
        int orow = (((ba2 >> 4) << 8) + t) * 16 + (ba2 & 15);
        out[orow * 30 + col] = acc5[nf][rr] + bias;
      }
    }
  }
}

extern "C" void kernel_launch(void* const* d_in, const int* in_sizes, int n_in,
                              void* d_out, int out_size, void* d_ws, size_t ws_size,
                              hipStream_t stream) {
  const float* inp = (const float*)d_in[0];
  const float* hid = (const float*)d_in[1];
  const float* w1  = (const float*)d_in[2];
  const float* b1  = (const float*)d_in[3];
  const float* w2  = (const float*)d_in[4];
  const float* b2  = (const float*)d_in[5];
  const float* w3  = (const float*)d_in[6];
  const float* b3  = (const float*)d_in[7];
  const float* w4  = (const float*)d_in[8];
  const float* b4  = (const float*)d_in[9];
  const float* w5  = (const float*)d_in[10];
  const float* b5  = (const float*)d_in[11];

  char* ws = (char*)d_ws;
  short* wp   = (short*)ws;
  short* w1p  = wp;
  short* w2p  = wp + W2P_OFF;
  short* w5p  = wp + W5P_OFF;
  unsigned char* w3p8 = (unsigned char*)(ws + W3P8_BYTE_OFF);
  unsigned char* seq8 = (unsigned char*)(ws + SEQ8_BYTE_OFF);
  unsigned char* w4p8 = (unsigned char*)(ws + W4P8_BYTE_OFF);
  unsigned char* h3p8 = (unsigned char*)(ws + BIG_BYTE_OFF);
  unsigned char* w1p8 = h3p8;               // dead once win writes h3p8 (after enc)
  unsigned char* w2p8 = w1p8 + 524288;
  float* out  = (float*)d_out;

  prep_kernel   <<<3552, 256, 0, stream>>>(w1, w2, w3, w4, w5, hid,
                                           wp, w1p8, w3p8, w4p8, seq8);
  enc_kernel    <<<2048, 512, 0, stream>>>(inp, w1p8, b1, w2p8, b2, seq8);
  enc_hi_kernel <<<224, 256, 0, stream>>>(inp, w1p, b1, w2p, b2, out);
  win_kernel    <<<1024, 512, 0, stream>>>(seq8, w3p8, b3, h3p8);
  dec_kernel    <<<1024, 512, 0, stream>>>(h3p8, w4p8, b4, w5p, b5, out);
}